// Round 1
// baseline (445.095 us; speedup 1.0000x reference)
//
#include <hip/hip_runtime.h>
#include <cstdint>
#include <cstddef>

#define HID 512
#define NSE 960
#define NB  32768
#define BM  32
#define ZROW 520   // ushort per LDS row for z_hi/z_lo (512 + 8 pad)
#define UROW 516   // dwords per LDS row for Rz / packed-u (512 + 4 pad)

typedef __attribute__((ext_vector_type(4))) float f32x4;
typedef __attribute__((ext_vector_type(8))) short short8;
typedef __attribute__((ext_vector_type(4))) unsigned short us4;
typedef __attribute__((ext_vector_type(4))) unsigned int u32x4;

// ---- bf16 split helpers (RNE) ----
__device__ __forceinline__ unsigned short bf16_rne(float x) {
  unsigned int u = __builtin_bit_cast(unsigned int, x);
  u += 0x7FFFu + ((u >> 16) & 1u);
  return (unsigned short)(u >> 16);
}
__device__ __forceinline__ float bf16_f32(unsigned short b) {
  return __builtin_bit_cast(float, (unsigned int)b << 16);
}
__device__ __forceinline__ void split_f32(float x, unsigned short &h, unsigned short &l) {
  h = bf16_rne(x);
  l = bf16_rne(x - bf16_f32(h));
}

// ---- ws layout (bytes) ----
#define WS_RH 0u
#define WS_RL (512u * 512u * 2u)            // 524288
#define WS_WH (2u * 512u * 512u * 2u)       // 1048576
#define WS_WL (WS_WH + 960u * 512u * 2u)    // 2031616
#define WS_FLAG (WS_WL + 960u * 512u * 2u)  // 3014656

__global__ void init_flag_kernel(unsigned int* f) { *f = 0u; }

__global__ void prep_kernel(const float* __restrict__ R, const float* __restrict__ D,
                            unsigned short* __restrict__ Rh, unsigned short* __restrict__ Rl,
                            unsigned short* __restrict__ Wh, unsigned short* __restrict__ Wl,
                            unsigned int* __restrict__ wlo_flag) {
  int i = blockIdx.x * 256 + threadIdx.x;
  if (i < HID * HID) {
    unsigned short h, l; split_f32(R[i], h, l);
    Rh[i] = h; Rl[i] = l;
  }
  int j = i - HID * HID;
  if (j >= 0 && j < NSE * HID) {
    float d = D[j];
    unsigned short h, l; split_f32(d * d, h, l);
    Wh[j] = h; Wl[j] = l;
    if (l != 0) atomicOr(wlo_flag, 1u);   // wave-coalesced by compiler; zero atomics when W bf16-exact
  }
}

// GEMM2 inner loop, templated on whether W_lo is nonzero anywhere.
template <bool WLO>
__device__ __forceinline__ void run_gemm2(const unsigned int* ub,
                                          const unsigned short* __restrict__ wh0,
                                          const unsigned short* __restrict__ wl0,
                                          int lr, int lg,
                                          f32x4 (&acc)[2][15]) {
  for (int ks = 0; ks < 16; ++ks) {
    const int kb = ks * 32;
    short8 uh[2], ul[2];
#pragma unroll
    for (int mi = 0; mi < 2; ++mi) {
      const unsigned int* p = ub + (mi * 16 + lr) * UROW + kb + lg * 8;
      u32x4 p0 = *(const u32x4*)(p);
      u32x4 p1 = *(const u32x4*)(p + 4);
      short8 h, l;
#pragma unroll
      for (int q = 0; q < 4; ++q) {
        h[q]     = (short)(p0[q] & 0xFFFFu);
        l[q]     = (short)(p0[q] >> 16);
        h[q + 4] = (short)(p1[q] & 0xFFFFu);
        l[q + 4] = (short)(p1[q] >> 16);
      }
      uh[mi] = h; ul[mi] = l;
    }
#pragma unroll
    for (int ni = 0; ni < 15; ++ni) {
      short8 bh = *(const short8*)(wh0 + ni * 16 * HID + kb);
#pragma unroll
      for (int mi = 0; mi < 2; ++mi) {
        acc[mi][ni] = __builtin_amdgcn_mfma_f32_16x16x32_bf16(uh[mi], bh, acc[mi][ni], 0, 0, 0);
        acc[mi][ni] = __builtin_amdgcn_mfma_f32_16x16x32_bf16(ul[mi], bh, acc[mi][ni], 0, 0, 0);
      }
      if (WLO) {
        short8 bl = *(const short8*)(wl0 + ni * 16 * HID + kb);
#pragma unroll
        for (int mi = 0; mi < 2; ++mi)
          acc[mi][ni] = __builtin_amdgcn_mfma_f32_16x16x32_bf16(uh[mi], bl, acc[mi][ni], 0, 0, 0);
      }
    }
  }
}

__global__ __launch_bounds__(256, 2)
void fused_dedicom(const float* __restrict__ zi, const float* __restrict__ zj,
                   const unsigned short* __restrict__ Rh, const unsigned short* __restrict__ Rl,
                   const unsigned short* __restrict__ Wh, const unsigned short* __restrict__ Wl,
                   const unsigned int* __restrict__ wlo_flag,
                   float* __restrict__ out) {
  // 66560 B: phase 1 = z_hi/z_lo bf16 [32][520]x2; phase 2 = Rz f32 -> packed u [32][516]
  __shared__ __align__(16) unsigned char smem[2 * BM * ZROW * 2];
  unsigned short* zh = (unsigned short*)smem;
  unsigned short* zl = zh + BM * ZROW;
  float*        uf = (float*)smem;
  unsigned int* ub = (unsigned int*)smem;

  const int tid  = threadIdx.x;
  const int wave = tid >> 6;
  const int lane = tid & 63;
  const int lr   = lane & 15;   // fragment row/col
  const int lg   = lane >> 4;   // 4-lane-group -> k-subblock / C row group
  const size_t brow = (size_t)blockIdx.x * BM;

  // ---- stage z_j, split to bf16 hi/lo in LDS (coalesced f32x4 reads) ----
  const float* zjB = zj + brow * HID;
#pragma unroll
  for (int it = 0; it < 16; ++it) {
    int flat = it * 1024 + tid * 4;
    f32x4 v = *(const f32x4*)(zjB + flat);
    int row = flat >> 9;
    int k = flat & (HID - 1);
    us4 hv, lv;
#pragma unroll
    for (int q = 0; q < 4; ++q) {
      unsigned short hh, ll; split_f32(v[q], hh, ll);
      hv[q] = hh; lv[q] = ll;
    }
    *(us4*)(zh + row * ZROW + k) = hv;
    *(us4*)(zl + row * ZROW + k) = lv;
  }
  __syncthreads();

  // ---- GEMM1: Rz[32][512] = zj @ R^T ; wave owns cols [wave*128, +128) ----
  const int wn0 = wave * 128;
  f32x4 acc1[2][8];
#pragma unroll
  for (int mi = 0; mi < 2; ++mi)
#pragma unroll
    for (int ni = 0; ni < 8; ++ni)
      acc1[mi][ni] = f32x4{0.f, 0.f, 0.f, 0.f};

  const unsigned short* rh0 = Rh + (size_t)(wn0 + lr) * HID + lg * 8;
  const unsigned short* rl0 = Rl + (size_t)(wn0 + lr) * HID + lg * 8;

  for (int ks = 0; ks < 16; ++ks) {
    const int kb = ks * 32;
    short8 ah[2], al[2];
#pragma unroll
    for (int mi = 0; mi < 2; ++mi) {
      int aoff = (mi * 16 + lr) * ZROW + kb + lg * 8;
      ah[mi] = *(const short8*)(zh + aoff);
      al[mi] = *(const short8*)(zl + aoff);
    }
#pragma unroll
    for (int ni = 0; ni < 8; ++ni) {
      short8 bh = *(const short8*)(rh0 + ni * 16 * HID + kb);
      short8 bl = *(const short8*)(rl0 + ni * 16 * HID + kb);
#pragma unroll
      for (int mi = 0; mi < 2; ++mi) {
        acc1[mi][ni] = __builtin_amdgcn_mfma_f32_16x16x32_bf16(ah[mi], bh, acc1[mi][ni], 0, 0, 0);
        acc1[mi][ni] = __builtin_amdgcn_mfma_f32_16x16x32_bf16(al[mi], bh, acc1[mi][ni], 0, 0, 0);
        acc1[mi][ni] = __builtin_amdgcn_mfma_f32_16x16x32_bf16(ah[mi], bl, acc1[mi][ni], 0, 0, 0);
      }
    }
  }
  __syncthreads();   // all waves done reading z staging

  // ---- spill Rz (f32) into LDS, overwriting z staging ----
#pragma unroll
  for (int mi = 0; mi < 2; ++mi)
#pragma unroll
    for (int ni = 0; ni < 8; ++ni)
#pragma unroll
      for (int q = 0; q < 4; ++q) {
        int row = mi * 16 + lg * 4 + q;
        int col = wn0 + ni * 16 + lr;
        uf[row * UROW + col] = acc1[mi][ni][q];
      }
  __syncthreads();

  // ---- u = z_i ⊙ Rz, split & pack (hi|lo<<16) in place; z_i coalesced from HBM ----
  const float* ziB = zi + brow * HID;
#pragma unroll
  for (int it = 0; it < 16; ++it) {
    int flat = it * 1024 + tid * 4;
    int row = flat >> 9;
    int k = flat & (HID - 1);
    f32x4 z = *(const f32x4*)(ziB + flat);
    int idx = row * UROW + k;
    f32x4 rz = *(const f32x4*)(uf + idx);
    f32x4 pkv;
#pragma unroll
    for (int q = 0; q < 4; ++q) {
      float u = z[q] * rz[q];
      unsigned short hh, ll; split_f32(u, hh, ll);
      pkv[q] = __builtin_bit_cast(float, (unsigned int)hh | ((unsigned int)ll << 16));
    }
    *(f32x4*)(uf + idx) = pkv;   // same-type store -> no strict-aliasing reorder hazard
  }
  __syncthreads();

  // ---- GEMM2: scores[32][960] = u @ W^T ; wave owns cols [wave*240, +240) ----
  f32x4 acc2[2][15];
#pragma unroll
  for (int mi = 0; mi < 2; ++mi)
#pragma unroll
    for (int ni = 0; ni < 15; ++ni)
      acc2[mi][ni] = f32x4{0.f, 0.f, 0.f, 0.f};

  const unsigned short* wh0 = Wh + (size_t)(wave * 240 + lr) * HID + lg * 8;
  const unsigned short* wl0 = Wl + (size_t)(wave * 240 + lr) * HID + lg * 8;

  if (*wlo_flag != 0u)
    run_gemm2<true>(ub, wh0, wl0, lr, lg, acc2);
  else
    run_gemm2<false>(ub, wh0, wl0, lr, lg, acc2);

  // ---- sigmoid + store ----
  float* outB = out + brow * NSE;
#pragma unroll
  for (int mi = 0; mi < 2; ++mi)
#pragma unroll
    for (int ni = 0; ni < 15; ++ni)
#pragma unroll
      for (int q = 0; q < 4; ++q) {
        int row = mi * 16 + lg * 4 + q;
        int col = wave * 240 + ni * 16 + lr;
        float s = acc2[mi][ni][q];
        outB[(size_t)row * NSE + col] = 1.0f / (1.0f + __expf(-s));
      }
}

extern "C" void kernel_launch(void* const* d_in, const int* in_sizes, int n_in,
                              void* d_out, int out_size, void* d_ws, size_t ws_size,
                              hipStream_t stream) {
  const float* zi = (const float*)d_in[0];
  const float* zj = (const float*)d_in[1];
  const float* R  = (const float*)d_in[2];
  const float* D  = (const float*)d_in[3];
  float* out = (float*)d_out;

  unsigned char* ws = (unsigned char*)d_ws;
  unsigned short* Rh = (unsigned short*)(ws + WS_RH);
  unsigned short* Rl = (unsigned short*)(ws + WS_RL);
  unsigned short* Wh = (unsigned short*)(ws + WS_WH);
  unsigned short* Wl = (unsigned short*)(ws + WS_WL);
  unsigned int*  flag = (unsigned int*)(ws + WS_FLAG);

  init_flag_kernel<<<1, 1, 0, stream>>>(flag);

  int prep_total = HID * HID + NSE * HID;
  prep_kernel<<<(prep_total + 255) / 256, 256, 0, stream>>>(R, D, Rh, Rl, Wh, Wl, flag);

  fused_dedicom<<<NB / BM, 256, 0, stream>>>(zi, zj, Rh, Rl, Wh, Wl, flag, out);
}

// Round 2
// 313.567 us; speedup vs baseline: 1.4195x; 1.4195x over previous
//
#include <hip/hip_runtime.h>
#include <cstdint>
#include <cstddef>

#define HID 512
#define NSE 960
#define NB  32768
#define BM  32
#define ZROW 520   // halves per LDS row (512 + 8 pad)

typedef __attribute__((ext_vector_type(4))) float f32x4;
typedef __attribute__((ext_vector_type(8))) _Float16 h8;
typedef __attribute__((ext_vector_type(4))) _Float16 h4;

// ---- ws layout (bytes) ----
// RTh: 512x512 fp16 frag-layout   @ 0        (524288 B)
// WTh: 960x512 fp16 frag-layout   @ 524288   (983040 B)
// WTl: 960x512 fp16 frag-layout   @ 1507328  (983040 B)
// flag: u32                       @ 2490368
#define WS_RTH 0u
#define WS_WTH 524288u
#define WS_WTL 1507328u
#define WS_FLAG 2490368u

__global__ void init_flag_kernel(unsigned int* f) { *f = 0u; }

// Builds fragment-major layouts: elem index = ((panel*16 + ks)*64 + lane)*8 + e
// maps to  M[row = panel*16 + (lane&15)][k = ks*32 + (lane>>4)*8 + e].
// A wave's B-fragment load in the main kernel is then 64 lanes x 16 B fully
// contiguous (one 1 KB coalesced transaction).
__global__ void prep_kernel(const float* __restrict__ R, const float* __restrict__ D,
                            _Float16* __restrict__ RTh, _Float16* __restrict__ WTh,
                            _Float16* __restrict__ WTl, unsigned int* __restrict__ flag) {
  int t = blockIdx.x * 256 + threadIdx.x;
  int lane = t & 63;
  int ks   = (t >> 6) & 15;
  int rr   = lane & 15;
  int k0   = ks * 32 + (lane >> 4) * 8;
  if (t < 32768) {                       // R: 512*512/8 frag8s
    int c = (t >> 10) * 16 + rr;
    const float* src = R + (size_t)c * HID + k0;
    h8 hv;
#pragma unroll
    for (int e = 0; e < 8; ++e) hv[e] = (_Float16)src[e];
    *(h8*)(RTh + (size_t)t * 8) = hv;
  } else if (t < 32768 + 61440) {        // W = D*D: 960*512/8 frag8s
    int o = t - 32768;
    int r = (o >> 10) * 16 + rr;
    const float* src = D + (size_t)r * HID + k0;
    h8 hv, lv;
    bool any = false;
#pragma unroll
    for (int e = 0; e < 8; ++e) {
      float d = src[e];
      float w = d * d;
      _Float16 hh = (_Float16)w;
      _Float16 ll = (_Float16)(w - (float)hh);
      hv[e] = hh; lv[e] = ll;
      any = any || ((float)ll != 0.0f);
    }
    *(h8*)(WTh + (size_t)o * 8) = hv;
    *(h8*)(WTl + (size_t)o * 8) = lv;
    if (any) atomicOr(flag, 1u);
  }
}

template <bool WLO>
__device__ __forceinline__ void gemm2_body(const _Float16* uhL, const _Float16* ulL,
                                           const _Float16* __restrict__ WThb,
                                           const _Float16* __restrict__ WTlb,
                                           int a0, int a1,
                                           f32x4 (&acc)[2][15]) {
#pragma unroll 2
  for (int ks = 0; ks < 16; ++ks) {
    const int ko = ks * 32;
    h8 uh0 = *(const h8*)(uhL + a0 + ko);
    h8 uh1 = *(const h8*)(uhL + a1 + ko);
    h8 ul0 = *(const h8*)(ulL + a0 + ko);
    h8 ul1 = *(const h8*)(ulL + a1 + ko);
#pragma unroll
    for (int ni = 0; ni < 15; ++ni) {
      h8 bh = *(const h8*)(WThb + ni * 8192 + ks * 512);
      acc[0][ni] = __builtin_amdgcn_mfma_f32_16x16x32_f16(uh0, bh, acc[0][ni], 0, 0, 0);
      acc[0][ni] = __builtin_amdgcn_mfma_f32_16x16x32_f16(ul0, bh, acc[0][ni], 0, 0, 0);
      acc[1][ni] = __builtin_amdgcn_mfma_f32_16x16x32_f16(uh1, bh, acc[1][ni], 0, 0, 0);
      acc[1][ni] = __builtin_amdgcn_mfma_f32_16x16x32_f16(ul1, bh, acc[1][ni], 0, 0, 0);
      if (WLO) {
        h8 bl = *(const h8*)(WTlb + ni * 8192 + ks * 512);
        acc[0][ni] = __builtin_amdgcn_mfma_f32_16x16x32_f16(uh0, bl, acc[0][ni], 0, 0, 0);
        acc[1][ni] = __builtin_amdgcn_mfma_f32_16x16x32_f16(uh1, bl, acc[1][ni], 0, 0, 0);
      }
    }
  }
}

__global__ __launch_bounds__(256, 2)
void fused_dedicom(const float* __restrict__ zi, const float* __restrict__ zj,
                   const _Float16* __restrict__ RTh, const _Float16* __restrict__ WTh,
                   const _Float16* __restrict__ WTl, const unsigned int* __restrict__ flag,
                   float* __restrict__ out) {
  // phase 1: zh/zl = fp16 split of z_j   [32][520] x2  (66560 B)
  // phase 3: same buffers reused as uh/ul
  __shared__ _Float16 sm[2 * BM * ZROW];
  _Float16* zh = sm;
  _Float16* zl = sm + BM * ZROW;

  const int tid  = threadIdx.x;
  const int wave = tid >> 6;
  const int lane = tid & 63;
  const int lr   = lane & 15;
  const int lg   = lane >> 4;
  const size_t brow = (size_t)blockIdx.x * BM;

  // ---- stage z_j -> fp16 hi/lo in LDS (coalesced f32x4 reads) ----
  const float* zjB = zj + brow * HID;
#pragma unroll
  for (int it = 0; it < 16; ++it) {
    int flat = it * 1024 + tid * 4;
    f32x4 v = *(const f32x4*)(zjB + flat);
    int row = flat >> 9;
    int k = flat & (HID - 1);
    h4 hv, lv;
#pragma unroll
    for (int q = 0; q < 4; ++q) {
      _Float16 hh = (_Float16)v[q];
      hv[q] = hh;
      lv[q] = (_Float16)(v[q] - (float)hh);
    }
    *(h4*)(zh + row * ZROW + k) = hv;
    *(h4*)(zl + row * ZROW + k) = lv;
  }
  __syncthreads();

  // ---- GEMM1: Rz = zj @ R^T, 2-term (zh*Rh + zl*Rh); wave owns 128 cols ----
  f32x4 acc1[2][8];
#pragma unroll
  for (int mi = 0; mi < 2; ++mi)
#pragma unroll
    for (int ni = 0; ni < 8; ++ni) acc1[mi][ni] = f32x4{0.f, 0.f, 0.f, 0.f};

  const _Float16* RTb = RTh + (size_t)wave * 65536 + (size_t)lane * 8;  // 8 panels * 8192
  const int a0 = lr * ZROW + lg * 8;
  const int a1 = (16 + lr) * ZROW + lg * 8;

#pragma unroll 4
  for (int ks = 0; ks < 16; ++ks) {
    const int ko = ks * 32;
    h8 ah0 = *(const h8*)(zh + a0 + ko);
    h8 ah1 = *(const h8*)(zh + a1 + ko);
    h8 al0 = *(const h8*)(zl + a0 + ko);
    h8 al1 = *(const h8*)(zl + a1 + ko);
#pragma unroll
    for (int ni = 0; ni < 8; ++ni) {
      h8 bh = *(const h8*)(RTb + ni * 8192 + ks * 512);  // 1 KB coalesced
      acc1[0][ni] = __builtin_amdgcn_mfma_f32_16x16x32_f16(ah0, bh, acc1[0][ni], 0, 0, 0);
      acc1[0][ni] = __builtin_amdgcn_mfma_f32_16x16x32_f16(al0, bh, acc1[0][ni], 0, 0, 0);
      acc1[1][ni] = __builtin_amdgcn_mfma_f32_16x16x32_f16(ah1, bh, acc1[1][ni], 0, 0, 0);
      acc1[1][ni] = __builtin_amdgcn_mfma_f32_16x16x32_f16(al1, bh, acc1[1][ni], 0, 0, 0);
    }
  }
  __syncthreads();   // all waves done reading z staging

  // ---- u = z_i ⊙ Rz from registers; split fp16; scatter into frag-layout LDS ----
  const int wn0 = wave * 128;
#pragma unroll
  for (int mi = 0; mi < 2; ++mi)
#pragma unroll
    for (int ni = 0; ni < 8; ++ni) {
      int col = wn0 + ni * 16 + lr;
#pragma unroll
      for (int q = 0; q < 4; ++q) {
        int row = mi * 16 + lg * 4 + q;
        float ziv = zi[(brow + row) * HID + col];
        float u = ziv * acc1[mi][ni][q];
        _Float16 hh = (_Float16)u;
        zh[row * ZROW + col] = hh;                       // uh
        zl[row * ZROW + col] = (_Float16)(u - (float)hh); // ul
      }
    }
  __syncthreads();

  // ---- GEMM2: scores = u @ W^T, 2-term (+wl term if flag); wave owns 240 cols ----
  f32x4 acc2[2][15];
#pragma unroll
  for (int mi = 0; mi < 2; ++mi)
#pragma unroll
    for (int ni = 0; ni < 15; ++ni) acc2[mi][ni] = f32x4{0.f, 0.f, 0.f, 0.f};

  const _Float16* WThb = WTh + (size_t)wave * 15 * 8192 + (size_t)lane * 8;
  const _Float16* WTlb = WTl + (size_t)wave * 15 * 8192 + (size_t)lane * 8;

  if (*flag != 0u)
    gemm2_body<true>(zh, zl, WThb, WTlb, a0, a1, acc2);
  else
    gemm2_body<false>(zh, zl, WThb, WTlb, a0, a1, acc2);

  // ---- sigmoid + store ----
  float* outB = out + brow * NSE;
#pragma unroll
  for (int mi = 0; mi < 2; ++mi)
#pragma unroll
    for (int ni = 0; ni < 15; ++ni)
#pragma unroll
      for (int q = 0; q < 4; ++q) {
        int row = mi * 16 + lg * 4 + q;
        int col = wave * 240 + ni * 16 + lr;
        float s = acc2[mi][ni][q];
        outB[(size_t)row * NSE + col] = 1.0f / (1.0f + __expf(-s));
      }
}

extern "C" void kernel_launch(void* const* d_in, const int* in_sizes, int n_in,
                              void* d_out, int out_size, void* d_ws, size_t ws_size,
                              hipStream_t stream) {
  const float* zi = (const float*)d_in[0];
  const float* zj = (const float*)d_in[1];
  const float* R  = (const float*)d_in[2];
  const float* D  = (const float*)d_in[3];
  float* out = (float*)d_out;

  unsigned char* ws = (unsigned char*)d_ws;
  _Float16* RTh = (_Float16*)(ws + WS_RTH);
  _Float16* WTh = (_Float16*)(ws + WS_WTH);
  _Float16* WTl = (_Float16*)(ws + WS_WTL);
  unsigned int* flag = (unsigned int*)(ws + WS_FLAG);

  init_flag_kernel<<<1, 1, 0, stream>>>(flag);
  prep_kernel<<<368, 256, 0, stream>>>(R, D, RTh, WTh, WTl, flag);  // 368*256 = 94208
  fused_dedicom<<<NB / BM, 256, 0, stream>>>(zi, zj, RTh, WTh, WTl, flag, out);
}

// Round 3
// 296.921 us; speedup vs baseline: 1.4990x; 1.0561x over previous
//
#include <hip/hip_runtime.h>
#include <cstdint>
#include <cstddef>

#define HID 512
#define NSE 960
#define NB  32768
#define BM  64
#define ZROW 520   // halves per LDS row (512 + 8 pad)

typedef __attribute__((ext_vector_type(4))) float f32x4;
typedef __attribute__((ext_vector_type(8))) _Float16 h8;
typedef __attribute__((ext_vector_type(4))) _Float16 h4;

// ---- ws layout (bytes) ----
#define WS_RTH 0u
#define WS_WTH 524288u
#define WS_WTL 1507328u
#define WS_FLAG 2490368u

__global__ void init_flag_kernel(unsigned int* f) { *f = 0u; }

// Fragment-major: elem ((panel*16 + ks)*64 + lane)*8 + e  <->
//   M[row = panel*16 + (lane&15)][k = ks*32 + (lane>>4)*8 + e]
__global__ void prep_kernel(const float* __restrict__ R, const float* __restrict__ D,
                            _Float16* __restrict__ RTh, _Float16* __restrict__ WTh,
                            _Float16* __restrict__ WTl, unsigned int* __restrict__ flag) {
  int t = blockIdx.x * 256 + threadIdx.x;
  int lane = t & 63;
  int ks   = (t >> 6) & 15;
  int rr   = lane & 15;
  int k0   = ks * 32 + (lane >> 4) * 8;
  if (t < 32768) {                       // R: 512*512/8 frag8s
    int c = (t >> 10) * 16 + rr;
    const float* src = R + (size_t)c * HID + k0;
    h8 hv;
#pragma unroll
    for (int e = 0; e < 8; ++e) hv[e] = (_Float16)src[e];
    *(h8*)(RTh + (size_t)t * 8) = hv;
  } else if (t < 32768 + 61440) {        // W = D*D: 960*512/8 frag8s
    int o = t - 32768;
    int r = (o >> 10) * 16 + rr;
    const float* src = D + (size_t)r * HID + k0;
    h8 hv, lv;
    bool any = false;
#pragma unroll
    for (int e = 0; e < 8; ++e) {
      float d = src[e];
      float w = d * d;
      _Float16 hh = (_Float16)w;
      _Float16 ll = (_Float16)(w - (float)hh);
      hv[e] = hh; lv[e] = ll;
      any = any || ((float)ll != 0.0f);
    }
    *(h8*)(WTh + (size_t)o * 8) = hv;
    *(h8*)(WTl + (size_t)o * 8) = lv;
    if (any) atomicOr(flag, 1u);
  }
}

template <int NPAN, bool WLO>
__device__ __forceinline__ void gemm2_body(const _Float16* zh, const _Float16* zl,
                                           const _Float16* __restrict__ WThb,
                                           const _Float16* __restrict__ WTlb,
                                           const int (&aoff)[4],
                                           f32x4 (&acc)[4][8]) {
#pragma unroll 2
  for (int ks = 0; ks < 16; ++ks) {
    const int ko = ks * 32;
    h8 uh[4], ul[4];
#pragma unroll
    for (int mi = 0; mi < 4; ++mi) {
      uh[mi] = *(const h8*)(zh + aoff[mi] + ko);
      ul[mi] = *(const h8*)(zl + aoff[mi] + ko);
    }
#pragma unroll
    for (int ni = 0; ni < NPAN; ++ni) {
      h8 bh = *(const h8*)(WThb + ni * 8192 + ks * 512);
#pragma unroll
      for (int mi = 0; mi < 4; ++mi) {
        acc[mi][ni] = __builtin_amdgcn_mfma_f32_16x16x32_f16(uh[mi], bh, acc[mi][ni], 0, 0, 0);
        acc[mi][ni] = __builtin_amdgcn_mfma_f32_16x16x32_f16(ul[mi], bh, acc[mi][ni], 0, 0, 0);
      }
      if (WLO) {
        h8 bl = *(const h8*)(WTlb + ni * 8192 + ks * 512);
#pragma unroll
        for (int mi = 0; mi < 4; ++mi)
          acc[mi][ni] = __builtin_amdgcn_mfma_f32_16x16x32_f16(uh[mi], bl, acc[mi][ni], 0, 0, 0);
      }
    }
  }
}

__global__ __launch_bounds__(512, 2)
void fused_dedicom(const float* __restrict__ zi, const float* __restrict__ zj,
                   const _Float16* __restrict__ RTh, const _Float16* __restrict__ WTh,
                   const _Float16* __restrict__ WTl, const unsigned int* __restrict__ flag,
                   float* __restrict__ out) {
  // zh/zl: fp16 hi/lo of z_j [64][520] x2 = 133120 B; reused as uh/ul for GEMM2
  __shared__ _Float16 sm[2 * BM * ZROW];
  _Float16* zh = sm;
  _Float16* zl = sm + BM * ZROW;

  const int tid  = threadIdx.x;
  const int wave = tid >> 6;
  const int lane = tid & 63;
  const int lr   = lane & 15;
  const int lg   = lane >> 4;
  const size_t brow = (size_t)blockIdx.x * BM;

  // ---- stage z_j -> fp16 hi/lo in LDS (coalesced f32x4 reads) ----
  const float* zjB = zj + brow * HID;
#pragma unroll
  for (int it = 0; it < 16; ++it) {
    int flat = it * 2048 + tid * 4;
    f32x4 v = *(const f32x4*)(zjB + flat);
    int row = flat >> 9;
    int k = flat & (HID - 1);
    h4 hv, lv;
#pragma unroll
    for (int q = 0; q < 4; ++q) {
      _Float16 hh = (_Float16)v[q];
      hv[q] = hh;
      lv[q] = (_Float16)(v[q] - (float)hh);
    }
    *(h4*)(zh + row * ZROW + k) = hv;
    *(h4*)(zl + row * ZROW + k) = lv;
  }

  // ---- z_i early prefetch (completes during GEMM1) ----
  const float* ziB = zi + brow * HID;
  float zir[4][4][4];
#pragma unroll
  for (int mi = 0; mi < 4; ++mi)
#pragma unroll
    for (int ni = 0; ni < 4; ++ni)
#pragma unroll
      for (int q = 0; q < 4; ++q)
        zir[mi][ni][q] = ziB[(size_t)(mi * 16 + lg * 4 + q) * HID + wave * 64 + ni * 16 + lr];

  __syncthreads();

  // ---- GEMM1: Rz = zj @ R^T, 2-term; wave owns 64 cols (4 panels) x 64 rows ----
  f32x4 acc1[4][4];
#pragma unroll
  for (int mi = 0; mi < 4; ++mi)
#pragma unroll
    for (int ni = 0; ni < 4; ++ni) acc1[mi][ni] = f32x4{0.f, 0.f, 0.f, 0.f};

  const _Float16* RTb = RTh + (size_t)wave * 4 * 8192 + (size_t)lane * 8;
  int aoff[4];
#pragma unroll
  for (int mi = 0; mi < 4; ++mi) aoff[mi] = (mi * 16 + lr) * ZROW + lg * 8;

#pragma unroll 2
  for (int ks = 0; ks < 16; ++ks) {
    const int ko = ks * 32;
    h8 ah[4], al[4];
#pragma unroll
    for (int mi = 0; mi < 4; ++mi) {
      ah[mi] = *(const h8*)(zh + aoff[mi] + ko);
      al[mi] = *(const h8*)(zl + aoff[mi] + ko);
    }
#pragma unroll
    for (int ni = 0; ni < 4; ++ni) {
      h8 bh = *(const h8*)(RTb + ni * 8192 + ks * 512);  // 1 KB coalesced
#pragma unroll
      for (int mi = 0; mi < 4; ++mi) {
        acc1[mi][ni] = __builtin_amdgcn_mfma_f32_16x16x32_f16(ah[mi], bh, acc1[mi][ni], 0, 0, 0);
        acc1[mi][ni] = __builtin_amdgcn_mfma_f32_16x16x32_f16(al[mi], bh, acc1[mi][ni], 0, 0, 0);
      }
    }
  }
  __syncthreads();   // all waves done reading z staging

  // ---- u = z_i ⊙ Rz from registers; split fp16; scatter into frag-layout LDS ----
#pragma unroll
  for (int mi = 0; mi < 4; ++mi)
#pragma unroll
    for (int ni = 0; ni < 4; ++ni) {
      int col = wave * 64 + ni * 16 + lr;
#pragma unroll
      for (int q = 0; q < 4; ++q) {
        int row = mi * 16 + lg * 4 + q;
        float u = zir[mi][ni][q] * acc1[mi][ni][q];
        _Float16 hh = (_Float16)u;
        zh[row * ZROW + col] = hh;
        zl[row * ZROW + col] = (_Float16)(u - (float)hh);
      }
    }
  __syncthreads();

  // ---- GEMM2: scores = u @ W^T; waves 0-3: 8 panels, waves 4-7: 7 panels ----
  f32x4 acc2[4][8];
#pragma unroll
  for (int mi = 0; mi < 4; ++mi)
#pragma unroll
    for (int ni = 0; ni < 8; ++ni) acc2[mi][ni] = f32x4{0.f, 0.f, 0.f, 0.f};

  const int p0   = (wave < 4) ? wave * 8 : 32 + (wave - 4) * 7;
  const int npan = (wave < 4) ? 8 : 7;
  const _Float16* WThb = WTh + (size_t)p0 * 8192 + (size_t)lane * 8;
  const _Float16* WTlb = WTl + (size_t)p0 * 8192 + (size_t)lane * 8;

  const bool wlo = (*flag != 0u);
  if (wave < 4) {
    if (wlo) gemm2_body<8, true >(zh, zl, WThb, WTlb, aoff, acc2);
    else     gemm2_body<8, false>(zh, zl, WThb, WTlb, aoff, acc2);
  } else {
    if (wlo) gemm2_body<7, true >(zh, zl, WThb, WTlb, aoff, acc2);
    else     gemm2_body<7, false>(zh, zl, WThb, WTlb, aoff, acc2);
  }

  // ---- sigmoid + store ----
  float* outB = out + brow * NSE;
#pragma unroll
  for (int mi = 0; mi < 4; ++mi)
#pragma unroll
    for (int ni = 0; ni < 8; ++ni) {
      if (ni < npan) {
        int col = (p0 + ni) * 16 + lr;
#pragma unroll
        for (int q = 0; q < 4; ++q) {
          int row = mi * 16 + lg * 4 + q;
          float s = acc2[mi][ni][q];
          outB[(size_t)row * NSE + col] = 1.0f / (1.0f + __expf(-s));
        }
      }
    }
}

extern "C" void kernel_launch(void* const* d_in, const int* in_sizes, int n_in,
                              void* d_out, int out_size, void* d_ws, size_t ws_size,
                              hipStream_t stream) {
  const float* zi = (const float*)d_in[0];
  const float* zj = (const float*)d_in[1];
  const float* R  = (const float*)d_in[2];
  const float* D  = (const float*)d_in[3];
  float* out = (float*)d_out;

  unsigned char* ws = (unsigned char*)d_ws;
  _Float16* RTh = (_Float16*)(ws + WS_RTH);
  _Float16* WTh = (_Float16*)(ws + WS_WTH);
  _Float16* WTl = (_Float16*)(ws + WS_WTL);
  unsigned int* flag = (unsigned int*)(ws + WS_FLAG);

  init_flag_kernel<<<1, 1, 0, stream>>>(flag);
  prep_kernel<<<368, 256, 0, stream>>>(R, D, RTh, WTh, WTl, flag);
  fused_dedicom<<<NB / BM, 512, 0, stream>>>(zi, zj, RTh, WTh, WTl, flag, out);
}

// Round 5
// 276.004 us; speedup vs baseline: 1.6126x; 1.0758x over previous
//
#include <hip/hip_runtime.h>
#include <cstdint>
#include <cstddef>

#define HID 512
#define NSE 960
#define NB  32768
#define BM  64
#define ZROW 520   // halves per LDS row (512 + 8 pad) -> 2-way-free bank spread on b128

typedef __attribute__((ext_vector_type(4))) float f32x4;
typedef __attribute__((ext_vector_type(8))) _Float16 h8;
typedef __attribute__((ext_vector_type(4))) _Float16 h4;

// ---- ws layout (bytes) ----
#define WS_RTH 0u
#define WS_WTH 524288u
#define WS_WTL 1507328u
#define WS_FLAG 2490368u

// Fragment-major: elem ((panel*16 + ks)*64 + lane)*8 + e  <->
//   M[row = panel*16 + (lane&15)][k = ks*32 + (lane>>4)*8 + e]
__global__ void prep_kernel(const float* __restrict__ R, const float* __restrict__ D,
                            _Float16* __restrict__ RTh, _Float16* __restrict__ WTh,
                            _Float16* __restrict__ WTl, unsigned int* __restrict__ flag) {
  int t = blockIdx.x * 256 + threadIdx.x;
  int lane = t & 63;
  int rr   = lane & 15;
  int ks   = (t >> 6) & 15;
  int k0   = ks * 32 + (lane >> 4) * 8;
  if (t < 32768) {                       // R: 512*512/8 frag8s
    int c = (t >> 10) * 16 + rr;
    const float* src = R + (size_t)c * HID + k0;
    h8 hv;
#pragma unroll
    for (int e = 0; e < 8; ++e) hv[e] = (_Float16)src[e];
    *(h8*)(RTh + (size_t)t * 8) = hv;
  } else if (t < 32768 + 61440) {        // W = D*D: 960*512/8 frag8s
    int o = t - 32768;
    int r = (o >> 10) * 16 + rr;
    const float* src = D + (size_t)r * HID + k0;
    h8 hv, lv;
    bool any = false;
#pragma unroll
    for (int e = 0; e < 8; ++e) {
      float d = src[e];
      float w = d * d;
      _Float16 hh = (_Float16)w;
      _Float16 ll = (_Float16)(w - (float)hh);
      hv[e] = hh; lv[e] = ll;
      any = any || ((float)ll != 0.0f);
    }
    *(h8*)(WTh + (size_t)o * 8) = hv;
    *(h8*)(WTl + (size_t)o * 8) = lv;
    if (any) atomicOr(flag, 1u);
  }
}

template <int NPAN, bool WLO>
__device__ __forceinline__ void gemm2_body(const _Float16* zh,
                                           const _Float16* __restrict__ WThb,
                                           const _Float16* __restrict__ WTlb,
                                           const int (&aoff)[4],
                                           f32x4 (&acc)[4][4]) {
#pragma unroll 2
  for (int ks = 0; ks < 16; ++ks) {
    const int ko = ks * 32;
    h8 uh[4];
#pragma unroll
    for (int mi = 0; mi < 4; ++mi) uh[mi] = *(const h8*)(zh + aoff[mi] + ko);
#pragma unroll
    for (int ni = 0; ni < NPAN; ++ni) {
      h8 bh = *(const h8*)(WThb + ni * 8192 + ks * 512);   // 1 KB coalesced
#pragma unroll
      for (int mi = 0; mi < 4; ++mi)
        acc[mi][ni] = __builtin_amdgcn_mfma_f32_16x16x32_f16(uh[mi], bh, acc[mi][ni], 0, 0, 0);
      if (WLO) {
        h8 bl = *(const h8*)(WTlb + ni * 8192 + ks * 512);
#pragma unroll
        for (int mi = 0; mi < 4; ++mi)
          acc[mi][ni] = __builtin_amdgcn_mfma_f32_16x16x32_f16(uh[mi], bl, acc[mi][ni], 0, 0, 0);
      }
    }
  }
}

__global__ __launch_bounds__(1024)
void fused_dedicom(const float* __restrict__ zi, const float* __restrict__ zj,
                   const _Float16* __restrict__ RTh, const _Float16* __restrict__ WTh,
                   const _Float16* __restrict__ WTl, const unsigned int* __restrict__ flag,
                   float* __restrict__ out) {
  // single fp16 plane: z_j staged, then reused as u   [64][520] = 66560 B
  __shared__ _Float16 zh[BM * ZROW];

  const int tid  = threadIdx.x;
  const int wave = tid >> 6;
  const int lane = tid & 63;
  const int lr   = lane & 15;
  const int lg   = lane >> 4;
  const size_t brow = (size_t)blockIdx.x * BM;

  // ---- stage z_j -> fp16 in LDS (coalesced f32x4 reads; 8 iters x 1024 thr) ----
  const float* zjB = zj + brow * HID;
#pragma unroll
  for (int it = 0; it < 8; ++it) {
    int flat = it * 4096 + tid * 4;
    f32x4 v = *(const f32x4*)(zjB + flat);
    int row = flat >> 9;
    int k = flat & (HID - 1);
    h4 hv;
#pragma unroll
    for (int q = 0; q < 4; ++q) hv[q] = (_Float16)v[q];
    *(h4*)(zh + row * ZROW + k) = hv;
  }
  __syncthreads();

  // ---- GEMM1: Rz = zj @ R^T (1-term); wave owns 64 rows x 32 cols (2 panels) ----
  f32x4 acc1[4][2];
#pragma unroll
  for (int mi = 0; mi < 4; ++mi)
#pragma unroll
    for (int ni = 0; ni < 2; ++ni) acc1[mi][ni] = f32x4{0.f, 0.f, 0.f, 0.f};

  const _Float16* RTb = RTh + (size_t)wave * 2 * 8192 + (size_t)lane * 8;
  int aoff[4];
#pragma unroll
  for (int mi = 0; mi < 4; ++mi) aoff[mi] = (mi * 16 + lr) * ZROW + lg * 8;

#pragma unroll 2
  for (int ks = 0; ks < 16; ++ks) {
    const int ko = ks * 32;
    h8 ah[4];
#pragma unroll
    for (int mi = 0; mi < 4; ++mi) ah[mi] = *(const h8*)(zh + aoff[mi] + ko);
#pragma unroll
    for (int ni = 0; ni < 2; ++ni) {
      h8 bh = *(const h8*)(RTb + ni * 8192 + ks * 512);
#pragma unroll
      for (int mi = 0; mi < 4; ++mi)
        acc1[mi][ni] = __builtin_amdgcn_mfma_f32_16x16x32_f16(ah[mi], bh, acc1[mi][ni], 0, 0, 0);
    }
  }
  __syncthreads();   // all waves done reading z staging

  // ---- u = z_i ⊙ Rz (from regs), fp16, scatter into frag-layout LDS ----
  const float* ziB = zi + brow * HID;
#pragma unroll
  for (int mi = 0; mi < 4; ++mi)
#pragma unroll
    for (int ni = 0; ni < 2; ++ni) {
      int col = wave * 32 + ni * 16 + lr;
#pragma unroll
      for (int q = 0; q < 4; ++q) {
        int row = mi * 16 + lg * 4 + q;
        float u = ziB[(size_t)row * HID + col] * acc1[mi][ni][q];
        zh[row * ZROW + col] = (_Float16)u;
      }
    }
  __syncthreads();

  // ---- GEMM2: scores = u @ W^T; 60 panels: waves 0-11 get 4, waves 12-15 get 3 ----
  f32x4 acc2[4][4];
#pragma unroll
  for (int mi = 0; mi < 4; ++mi)
#pragma unroll
    for (int ni = 0; ni < 4; ++ni) acc2[mi][ni] = f32x4{0.f, 0.f, 0.f, 0.f};

  const int p0   = (wave < 12) ? wave * 4 : 48 + (wave - 12) * 3;
  const int npan = (wave < 12) ? 4 : 3;
  const _Float16* WThb = WTh + (size_t)p0 * 8192 + (size_t)lane * 8;
  const _Float16* WTlb = WTl + (size_t)p0 * 8192 + (size_t)lane * 8;

  const bool wlo = (*flag != 0u);
  if (npan == 4) {
    if (wlo) gemm2_body<4, true >(zh, WThb, WTlb, aoff, acc2);
    else     gemm2_body<4, false>(zh, WThb, WTlb, aoff, acc2);
  } else {
    if (wlo) gemm2_body<3, true >(zh, WThb, WTlb, aoff, acc2);
    else     gemm2_body<3, false>(zh, WThb, WTlb, aoff, acc2);
  }

  // ---- sigmoid + store ----
  float* outB = out + brow * NSE;
#pragma unroll
  for (int mi = 0; mi < 4; ++mi)
#pragma unroll
    for (int ni = 0; ni < 4; ++ni) {
      if (ni < npan) {
        int col = (p0 + ni) * 16 + lr;
#pragma unroll
        for (int q = 0; q < 4; ++q) {
          int row = mi * 16 + lg * 4 + q;
          float s = acc2[mi][ni][q];
          outB[(size_t)row * NSE + col] = 1.0f / (1.0f + __expf(-s));
        }
      }
    }
}

extern "C" void kernel_launch(void* const* d_in, const int* in_sizes, int n_in,
                              void* d_out, int out_size, void* d_ws, size_t ws_size,
                              hipStream_t stream) {
  const float* zi = (const float*)d_in[0];
  const float* zj = (const float*)d_in[1];
  const float* R  = (const float*)d_in[2];
  const float* D  = (const float*)d_in[3];
  float* out = (float*)d_out;

  unsigned char* ws = (unsigned char*)d_ws;
  _Float16* RTh = (_Float16*)(ws + WS_RTH);
  _Float16* WTh = (_Float16*)(ws + WS_WTH);
  _Float16* WTl = (_Float16*)(ws + WS_WTL);
  unsigned int* flag = (unsigned int*)(ws + WS_FLAG);

  hipMemsetAsync(flag, 0, 4, stream);
  prep_kernel<<<368, 256, 0, stream>>>(R, D, RTh, WTh, WTl, flag);
  fused_dedicom<<<NB / BM, 1024, 0, stream>>>(zi, zj, RTh, WTh, WTl, flag, out);
}